// Round 1
// baseline (8630.149 us; speedup 1.0000x reference)
//
#include <hip/hip_runtime.h>
#include <hip/hip_bf16.h>

#define DIM 128

// ---------------- degree kernels ----------------
__global__ __launch_bounds__(256) void deg_init_kernel(float* __restrict__ deg, int N) {
    int i = blockIdx.x * 256 + threadIdx.x;
    if (i < N) deg[i] = 1.0f;  // self-loop
}

__global__ __launch_bounds__(256) void deg_count_kernel(const int* __restrict__ dst,
                                                        float* __restrict__ deg, int E) {
    int e = blockIdx.x * 256 + threadIdx.x;
    if (e < E) unsafeAtomicAdd(&deg[dst[e]], 1.0f);
}

__global__ __launch_bounds__(256) void deg_finish_kernel(float* __restrict__ deg, int N) {
    int i = blockIdx.x * 256 + threadIdx.x;
    if (i < N) deg[i] = 1.0f / sqrtf(deg[i]);
}

// ---------------- GEMM 128 -> 128 ----------------
// Y[n,:] = X[n,:] @ W  (optionally * dinv[n], + b, relu)
// Block: 256 threads, 32 rows/block. W (64KB) + X tile (16KB) in LDS -> 2 blocks/CU.
// Thread tile: 4 rows x 4 cols, k unrolled by 4 with float4 LDS reads.
template<bool SCALE, bool BIAS, bool RELU>
__global__ __launch_bounds__(256, 2) void gemm128_kernel(
    const float* __restrict__ X, const float* __restrict__ W,
    const float* __restrict__ b, const float* __restrict__ dinv,
    float* __restrict__ Y, int N)
{
    __shared__ float Wl[DIM * DIM];   // 64 KB
    __shared__ float Xs[32 * DIM];    // 16 KB
    const int tid = threadIdx.x;
    const int row0 = blockIdx.x * 32;

    for (int i = tid * 4; i < DIM * DIM; i += 256 * 4)
        *(float4*)&Wl[i] = *(const float4*)&W[i];

    for (int i = tid * 4; i < 32 * DIM; i += 256 * 4) {
        int r = row0 + (i >> 7);
        float4 v;
        if (r < N) v = *(const float4*)&X[row0 * DIM + i];
        else       v = float4{0.f, 0.f, 0.f, 0.f};
        *(float4*)&Xs[i] = v;
    }
    __syncthreads();

    const int j4 = (tid & 31) * 4;   // output col group
    const int r0 = (tid >> 5) * 4;   // row group within tile (0..28)

    float acc[4][4];
#pragma unroll
    for (int r = 0; r < 4; ++r)
#pragma unroll
        for (int c = 0; c < 4; ++c) acc[r][c] = 0.f;

    for (int k = 0; k < DIM; k += 4) {
        float4 xr[4], wr[4];
#pragma unroll
        for (int r = 0; r < 4; ++r) xr[r] = *(const float4*)&Xs[(r0 + r) * DIM + k];
#pragma unroll
        for (int kk = 0; kk < 4; ++kk) wr[kk] = *(const float4*)&Wl[(k + kk) * DIM + j4];
#pragma unroll
        for (int kk = 0; kk < 4; ++kk) {
#pragma unroll
            for (int r = 0; r < 4; ++r) {
                float xv = ((const float*)&xr[r])[kk];
                acc[r][0] = fmaf(xv, wr[kk].x, acc[r][0]);
                acc[r][1] = fmaf(xv, wr[kk].y, acc[r][1]);
                acc[r][2] = fmaf(xv, wr[kk].z, acc[r][2]);
                acc[r][3] = fmaf(xv, wr[kk].w, acc[r][3]);
            }
        }
    }

    float4 bb = float4{0.f, 0.f, 0.f, 0.f};
    if (BIAS) bb = *(const float4*)&b[j4];

#pragma unroll
    for (int r = 0; r < 4; ++r) {
        int row = row0 + r0 + r;
        if (row < N) {
            float s = SCALE ? dinv[row] : 1.0f;
            float4 o;
            o.x = acc[r][0] * s + bb.x;
            o.y = acc[r][1] * s + bb.y;
            o.z = acc[r][2] * s + bb.z;
            o.w = acc[r][3] * s + bb.w;
            if (RELU) {
                o.x = fmaxf(o.x, 0.f); o.y = fmaxf(o.y, 0.f);
                o.z = fmaxf(o.z, 0.f); o.w = fmaxf(o.w, 0.f);
            }
            *(float4*)&Y[row * DIM + j4] = o;
        }
    }
}

// ---------------- edge scatter: AGG[dst] += H[src] ----------------
// 32 lanes per edge, float4 gather + 4 dword atomics per lane.
__global__ __launch_bounds__(256) void scatter_kernel(
    const int* __restrict__ src, const int* __restrict__ dst,
    const float* __restrict__ H, float* __restrict__ AGG, int E)
{
    int t = blockIdx.x * 256 + threadIdx.x;
    int e = t >> 5;
    if (e >= E) return;
    int c = (t & 31) * 4;
    int s = src[e];
    int d = dst[e];
    float4 v = *(const float4*)&H[s * DIM + c];
    float* p = &AGG[d * DIM + c];
    unsafeAtomicAdd(p + 0, v.x);
    unsafeAtomicAdd(p + 1, v.y);
    unsafeAtomicAdd(p + 2, v.z);
    unsafeAtomicAdd(p + 3, v.w);
}

// ---------------- GCN epilogue: Y = relu(dinv*(AGG + H) + b), in-place on AGG ----------------
__global__ __launch_bounds__(256) void epilogue_kernel(
    float* __restrict__ AGG, const float* __restrict__ H,
    const float* __restrict__ b, const float* __restrict__ dinv, int N)
{
    int t = blockIdx.x * 256 + threadIdx.x;      // one float4 per thread
    int idx = t * 4;
    if (idx >= N * DIM) return;
    int row = idx >> 7;
    float s = dinv[row];
    float4 a = *(const float4*)&AGG[idx];
    float4 h = *(const float4*)&H[idx];
    float4 bb = *(const float4*)&b[idx & 127];
    float4 o;
    o.x = fmaxf(s * (a.x + h.x) + bb.x, 0.f);
    o.y = fmaxf(s * (a.y + h.y) + bb.y, 0.f);
    o.z = fmaxf(s * (a.z + h.z) + bb.z, 0.f);
    o.w = fmaxf(s * (a.w + h.w) + bb.w, 0.f);
    *(float4*)&AGG[idx] = o;
}

// ---------------- final 128 -> 10 GEMM ----------------
__global__ __launch_bounds__(256) void gemm_out_kernel(
    const float* __restrict__ X, const float* __restrict__ W,
    const float* __restrict__ b, float* __restrict__ out, int N)
{
    __shared__ float Wl[DIM * 10];   // 5 KB
    __shared__ float bl[16];
    __shared__ float Xs[64 * DIM];   // 32 KB
    int tid = threadIdx.x;
    for (int i = tid; i < DIM * 10; i += 256) Wl[i] = W[i];
    if (tid < 10) bl[tid] = b[tid];
    int row0 = blockIdx.x * 64;
    for (int i = tid * 4; i < 64 * DIM; i += 256 * 4) {
        int r = row0 + (i >> 7);
        float4 v;
        if (r < N) v = *(const float4*)&X[row0 * DIM + i];
        else       v = float4{0.f, 0.f, 0.f, 0.f};
        *(float4*)&Xs[i] = v;
    }
    __syncthreads();
    for (int oi = tid; oi < 64 * 10; oi += 256) {
        int r = oi / 10;
        int cc = oi - r * 10;
        int row = row0 + r;
        if (row >= N) continue;
        float acc = 0.f;
#pragma unroll 8
        for (int k = 0; k < DIM; ++k)
            acc = fmaf(Xs[r * DIM + k], Wl[k * 10 + cc], acc);
        out[row * 10 + cc] = acc + bl[cc];
    }
}

extern "C" void kernel_launch(void* const* d_in, const int* in_sizes, int n_in,
                              void* d_out, int out_size, void* d_ws, size_t ws_size,
                              hipStream_t stream) {
    const float* x   = (const float*)d_in[0];
    const int*   ei  = (const int*)  d_in[1];
    const float* W1  = (const float*)d_in[2];
    const float* b1  = (const float*)d_in[3];
    const float* W2  = (const float*)d_in[4];
    const float* b2  = (const float*)d_in[5];
    const float* W3  = (const float*)d_in[6];
    const float* b3  = (const float*)d_in[7];
    const float* fW1 = (const float*)d_in[8];
    const float* fb1 = (const float*)d_in[9];
    const float* fW2 = (const float*)d_in[10];
    const float* fb2 = (const float*)d_in[11];
    float* out = (float*)d_out;

    const int N = in_sizes[0] / DIM;     // 100000
    const int E = in_sizes[1] / 2;       // 1600000
    const int* srcI = ei;
    const int* dstI = ei + E;

    char* ws = (char*)d_ws;
    size_t NB = (size_t)N * DIM * sizeof(float);          // 51.2 MB
    size_t off0 = ((size_t)N * sizeof(float) + 1023) & ~(size_t)1023;
    float* dinv = (float*)ws;
    float* bufA = (float*)(ws + off0);
    float* bufB = (float*)(ws + off0 + NB);

    dim3 blk(256);
    int gN   = (N + 255) / 256;
    int gE   = (E + 255) / 256;
    int gRow = (N + 31) / 32;
    int gSc  = (int)(((long long)E * 32 + 255) / 256);
    int gEp  = (int)(((long long)N * DIM / 4 + 255) / 256);
    int gOut = (N + 63) / 64;

    // degrees -> dinv
    deg_init_kernel<<<gN, blk, 0, stream>>>(dinv, N);
    deg_count_kernel<<<gE, blk, 0, stream>>>(dstI, dinv, E);
    deg_finish_kernel<<<gN, blk, 0, stream>>>(dinv, N);

    // ---- GCN layer 1: x -> bufB
    gemm128_kernel<true, false, false><<<gRow, blk, 0, stream>>>(x, W1, nullptr, dinv, bufA, N);
    hipMemsetAsync(bufB, 0, NB, stream);
    scatter_kernel<<<gSc, blk, 0, stream>>>(srcI, dstI, bufA, bufB, E);
    epilogue_kernel<<<gEp, blk, 0, stream>>>(bufB, bufA, b1, dinv, N);

    // ---- GCN layer 2: bufB -> bufB
    gemm128_kernel<true, false, false><<<gRow, blk, 0, stream>>>(bufB, W2, nullptr, dinv, bufA, N);
    hipMemsetAsync(bufB, 0, NB, stream);
    scatter_kernel<<<gSc, blk, 0, stream>>>(srcI, dstI, bufA, bufB, E);
    epilogue_kernel<<<gEp, blk, 0, stream>>>(bufB, bufA, b2, dinv, N);

    // ---- GCN layer 3: bufB -> bufB
    gemm128_kernel<true, false, false><<<gRow, blk, 0, stream>>>(bufB, W3, nullptr, dinv, bufA, N);
    hipMemsetAsync(bufB, 0, NB, stream);
    scatter_kernel<<<gSc, blk, 0, stream>>>(srcI, dstI, bufA, bufB, E);
    epilogue_kernel<<<gEp, blk, 0, stream>>>(bufB, bufA, b3, dinv, N);

    // ---- FFN: relu(bufB @ fW1 + fb1) -> bufA ; bufA @ fW2 + fb2 -> out
    gemm128_kernel<false, true, true><<<gRow, blk, 0, stream>>>(bufB, fW1, fb1, nullptr, bufA, N);
    gemm_out_kernel<<<gOut, blk, 0, stream>>>(bufA, fW2, fb2, out, N);
}

// Round 2
// 947.751 us; speedup vs baseline: 9.1059x; 9.1059x over previous
//
#include <hip/hip_runtime.h>
#include <hip/hip_bf16.h>

#define DIM 128

// ---------------- degree / dinv ----------------
__global__ __launch_bounds__(256) void deg_count_kernel(const int* __restrict__ dst,
                                                        int* __restrict__ deg, int E) {
    int e = blockIdx.x * 256 + threadIdx.x;
    if (e < E) atomicAdd(&deg[dst[e]], 1);
}

__global__ __launch_bounds__(256) void dinv_kernel(const int* __restrict__ deg,
                                                   float* __restrict__ dinv, int N) {
    int i = blockIdx.x * 256 + threadIdx.x;
    if (i < N) dinv[i] = rsqrtf((float)(deg[i] + 1));   // +1 self-loop
}

// ---------------- exclusive scan (3-kernel, N ~ 100K) ----------------
__global__ __launch_bounds__(256) void scan_block_sums(const int* __restrict__ deg,
                                                       int* __restrict__ bsum, int N) {
    int i = blockIdx.x * 256 + threadIdx.x;
    int v = (i < N) ? deg[i] : 0;
#pragma unroll
    for (int off = 32; off; off >>= 1) v += __shfl_down(v, off);
    __shared__ int ws[4];
    if ((threadIdx.x & 63) == 0) ws[threadIdx.x >> 6] = v;
    __syncthreads();
    if (threadIdx.x == 0) bsum[blockIdx.x] = ws[0] + ws[1] + ws[2] + ws[3];
}

__global__ __launch_bounds__(256) void scan_bsum_kernel(int* __restrict__ bsum, int nb) {
    __shared__ int sm[256];
    __shared__ int carry_s;
    if (threadIdx.x == 0) carry_s = 0;
    __syncthreads();
    for (int base = 0; base < nb; base += 256) {
        int i = base + threadIdx.x;
        int v = (i < nb) ? bsum[i] : 0;
        int c = carry_s;
        sm[threadIdx.x] = v;
        __syncthreads();
        for (int off = 1; off < 256; off <<= 1) {
            int t = (threadIdx.x >= off) ? sm[threadIdx.x - off] : 0;
            __syncthreads();
            sm[threadIdx.x] += t;
            __syncthreads();
        }
        int incl = sm[threadIdx.x];
        if (i < nb) bsum[i] = c + incl - v;   // exclusive
        __syncthreads();
        if (threadIdx.x == 0) carry_s = c + sm[255];
        __syncthreads();
    }
}

__global__ __launch_bounds__(256) void scan_finish_kernel(const int* __restrict__ deg,
                                                          const int* __restrict__ bsum,
                                                          int* __restrict__ rowptr,
                                                          int* __restrict__ cursor, int N) {
    __shared__ int sm[256];
    int i = blockIdx.x * 256 + threadIdx.x;
    int v = (i < N) ? deg[i] : 0;
    sm[threadIdx.x] = v;
    __syncthreads();
    for (int off = 1; off < 256; off <<= 1) {
        int t = (threadIdx.x >= off) ? sm[threadIdx.x - off] : 0;
        __syncthreads();
        sm[threadIdx.x] += t;
        __syncthreads();
    }
    int excl = sm[threadIdx.x] - v + bsum[blockIdx.x];
    if (i < N) { rowptr[i] = excl; cursor[i] = excl; }
    if (i == N - 1) rowptr[N] = excl + v;   // == E
}

__global__ __launch_bounds__(256) void csr_fill_kernel(const int* __restrict__ src,
                                                       const int* __restrict__ dst,
                                                       int* __restrict__ cursor,
                                                       int* __restrict__ colidx, int E) {
    int e = blockIdx.x * 256 + threadIdx.x;
    if (e < E) {
        int p = atomicAdd(&cursor[dst[e]], 1);
        colidx[p] = src[e];
    }
}

// ---------------- GEMM 128 -> 128 ----------------
template<bool SCALE, bool BIAS, bool RELU>
__global__ __launch_bounds__(256, 2) void gemm128_kernel(
    const float* __restrict__ X, const float* __restrict__ W,
    const float* __restrict__ b, const float* __restrict__ dinv,
    float* __restrict__ Y, int N)
{
    __shared__ float Wl[DIM * DIM];   // 64 KB
    __shared__ float Xs[32 * DIM];    // 16 KB
    const int tid = threadIdx.x;
    const int row0 = blockIdx.x * 32;

    for (int i = tid * 4; i < DIM * DIM; i += 256 * 4)
        *(float4*)&Wl[i] = *(const float4*)&W[i];

    for (int i = tid * 4; i < 32 * DIM; i += 256 * 4) {
        int r = row0 + (i >> 7);
        float4 v;
        if (r < N) v = *(const float4*)&X[row0 * DIM + i];
        else       v = float4{0.f, 0.f, 0.f, 0.f};
        *(float4*)&Xs[i] = v;
    }
    __syncthreads();

    const int j4 = (tid & 31) * 4;
    const int r0 = (tid >> 5) * 4;

    float acc[4][4];
#pragma unroll
    for (int r = 0; r < 4; ++r)
#pragma unroll
        for (int c = 0; c < 4; ++c) acc[r][c] = 0.f;

    for (int k = 0; k < DIM; k += 4) {
        float4 xr[4], wr[4];
#pragma unroll
        for (int r = 0; r < 4; ++r) xr[r] = *(const float4*)&Xs[(r0 + r) * DIM + k];
#pragma unroll
        for (int kk = 0; kk < 4; ++kk) wr[kk] = *(const float4*)&Wl[(k + kk) * DIM + j4];
#pragma unroll
        for (int kk = 0; kk < 4; ++kk) {
#pragma unroll
            for (int r = 0; r < 4; ++r) {
                float xv = ((const float*)&xr[r])[kk];
                acc[r][0] = fmaf(xv, wr[kk].x, acc[r][0]);
                acc[r][1] = fmaf(xv, wr[kk].y, acc[r][1]);
                acc[r][2] = fmaf(xv, wr[kk].z, acc[r][2]);
                acc[r][3] = fmaf(xv, wr[kk].w, acc[r][3]);
            }
        }
    }

    float4 bb = float4{0.f, 0.f, 0.f, 0.f};
    if (BIAS) bb = *(const float4*)&b[j4];

#pragma unroll
    for (int r = 0; r < 4; ++r) {
        int row = row0 + r0 + r;
        if (row < N) {
            float s = SCALE ? dinv[row] : 1.0f;
            float4 o;
            o.x = acc[r][0] * s + bb.x;
            o.y = acc[r][1] * s + bb.y;
            o.z = acc[r][2] * s + bb.z;
            o.w = acc[r][3] * s + bb.w;
            if (RELU) {
                o.x = fmaxf(o.x, 0.f); o.y = fmaxf(o.y, 0.f);
                o.z = fmaxf(o.z, 0.f); o.w = fmaxf(o.w, 0.f);
            }
            *(float4*)&Y[row * DIM + j4] = o;
        }
    }
}

// ---------------- pull-gather + fused epilogue ----------------
// Y[i] = relu(dinv[i] * (H[i] + sum_{e in row i} H[colidx[e]]) + b)
// 32 lanes per node, float4 per lane.
__global__ __launch_bounds__(256) void gather_kernel(
    const int* __restrict__ rowptr, const int* __restrict__ colidx,
    const float* __restrict__ H, const float* __restrict__ b,
    const float* __restrict__ dinv, float* __restrict__ Y, int N)
{
    int t = blockIdx.x * 256 + threadIdx.x;
    int node = t >> 5;
    if (node >= N) return;
    int c = (t & 31) * 4;

    int beg = rowptr[node];
    int end = rowptr[node + 1];

    float4 acc = *(const float4*)&H[(size_t)node * DIM + c];   // self-loop
    int e = beg;
    for (; e + 1 < end; e += 2) {
        int s0 = colidx[e];
        int s1 = colidx[e + 1];
        float4 v0 = *(const float4*)&H[(size_t)s0 * DIM + c];
        float4 v1 = *(const float4*)&H[(size_t)s1 * DIM + c];
        acc.x += v0.x + v1.x; acc.y += v0.y + v1.y;
        acc.z += v0.z + v1.z; acc.w += v0.w + v1.w;
    }
    if (e < end) {
        int s0 = colidx[e];
        float4 v0 = *(const float4*)&H[(size_t)s0 * DIM + c];
        acc.x += v0.x; acc.y += v0.y; acc.z += v0.z; acc.w += v0.w;
    }

    float sc = dinv[node];
    float4 bb = *(const float4*)&b[c];
    float4 o;
    o.x = fmaxf(fmaf(acc.x, sc, bb.x), 0.f);
    o.y = fmaxf(fmaf(acc.y, sc, bb.y), 0.f);
    o.z = fmaxf(fmaf(acc.z, sc, bb.z), 0.f);
    o.w = fmaxf(fmaf(acc.w, sc, bb.w), 0.f);
    *(float4*)&Y[(size_t)node * DIM + c] = o;
}

// ---------------- final 128 -> 10 GEMM ----------------
__global__ __launch_bounds__(256) void gemm_out_kernel(
    const float* __restrict__ X, const float* __restrict__ W,
    const float* __restrict__ b, float* __restrict__ out, int N)
{
    __shared__ float Wl[DIM * 10];
    __shared__ float bl[16];
    __shared__ float Xs[64 * DIM];
    int tid = threadIdx.x;
    for (int i = tid; i < DIM * 10; i += 256) Wl[i] = W[i];
    if (tid < 10) bl[tid] = b[tid];
    int row0 = blockIdx.x * 64;
    for (int i = tid * 4; i < 64 * DIM; i += 256 * 4) {
        int r = row0 + (i >> 7);
        float4 v;
        if (r < N) v = *(const float4*)&X[row0 * DIM + i];
        else       v = float4{0.f, 0.f, 0.f, 0.f};
        *(float4*)&Xs[i] = v;
    }
    __syncthreads();
    for (int oi = tid; oi < 64 * 10; oi += 256) {
        int r = oi / 10;
        int cc = oi - r * 10;
        int row = row0 + r;
        if (row >= N) continue;
        float acc = 0.f;
#pragma unroll 8
        for (int k = 0; k < DIM; ++k)
            acc = fmaf(Xs[r * DIM + k], Wl[k * 10 + cc], acc);
        out[row * 10 + cc] = acc + bl[cc];
    }
}

extern "C" void kernel_launch(void* const* d_in, const int* in_sizes, int n_in,
                              void* d_out, int out_size, void* d_ws, size_t ws_size,
                              hipStream_t stream) {
    const float* x   = (const float*)d_in[0];
    const int*   ei  = (const int*)  d_in[1];
    const float* W1  = (const float*)d_in[2];
    const float* b1  = (const float*)d_in[3];
    const float* W2  = (const float*)d_in[4];
    const float* b2  = (const float*)d_in[5];
    const float* W3  = (const float*)d_in[6];
    const float* b3  = (const float*)d_in[7];
    const float* fW1 = (const float*)d_in[8];
    const float* fb1 = (const float*)d_in[9];
    const float* fW2 = (const float*)d_in[10];
    const float* fb2 = (const float*)d_in[11];
    float* out = (float*)d_out;

    const int N = in_sizes[0] / DIM;     // 100000
    const int E = in_sizes[1] / 2;       // 1600000
    const int* srcI = ei;
    const int* dstI = ei + E;
    const int nb = (N + 255) / 256;      // scan blocks

    // ---- workspace carve-up (256B aligned) ----
    char* ws = (char*)d_ws;
    size_t off = 0;
    auto carve = [&](size_t bytes) { void* p = ws + off; off = (off + bytes + 255) & ~(size_t)255; return p; };
    float* dinv   = (float*)carve((size_t)N * 4);
    int*   deg    = (int*)  carve((size_t)N * 4);
    int*   rowptr = (int*)  carve((size_t)(N + 1) * 4);
    int*   cursor = (int*)  carve((size_t)N * 4);
    int*   bsum   = (int*)  carve((size_t)nb * 4);
    int*   colidx = (int*)  carve((size_t)E * 4);
    float* bufA   = (float*)carve((size_t)N * DIM * 4);
    float* bufB   = (float*)carve((size_t)N * DIM * 4);

    dim3 blk(256);
    int gN   = (N + 255) / 256;
    int gE   = (E + 255) / 256;
    int gRow = (N + 31) / 32;
    int gGa  = (int)(((long long)N * 32 + 255) / 256);
    int gOut = (N + 63) / 64;

    // ---- CSR build (per launch; d_ws is re-poisoned every call) ----
    hipMemsetAsync(deg, 0, (size_t)N * 4, stream);
    deg_count_kernel<<<gE, blk, 0, stream>>>(dstI, deg, E);
    dinv_kernel<<<gN, blk, 0, stream>>>(deg, dinv, N);
    scan_block_sums<<<nb, blk, 0, stream>>>(deg, bsum, N);
    scan_bsum_kernel<<<1, blk, 0, stream>>>(bsum, nb);
    scan_finish_kernel<<<nb, blk, 0, stream>>>(deg, bsum, rowptr, cursor, N);
    csr_fill_kernel<<<gE, blk, 0, stream>>>(srcI, dstI, cursor, colidx, E);

    // ---- GCN layer 1: x -> bufB
    gemm128_kernel<true, false, false><<<gRow, blk, 0, stream>>>(x, W1, nullptr, dinv, bufA, N);
    gather_kernel<<<gGa, blk, 0, stream>>>(rowptr, colidx, bufA, b1, dinv, bufB, N);

    // ---- GCN layer 2
    gemm128_kernel<true, false, false><<<gRow, blk, 0, stream>>>(bufB, W2, nullptr, dinv, bufA, N);
    gather_kernel<<<gGa, blk, 0, stream>>>(rowptr, colidx, bufA, b2, dinv, bufB, N);

    // ---- GCN layer 3
    gemm128_kernel<true, false, false><<<gRow, blk, 0, stream>>>(bufB, W3, nullptr, dinv, bufA, N);
    gather_kernel<<<gGa, blk, 0, stream>>>(rowptr, colidx, bufA, b3, dinv, bufB, N);

    // ---- FFN head
    gemm128_kernel<false, true, true><<<gRow, blk, 0, stream>>>(bufB, fW1, fb1, nullptr, bufA, N);
    gemm_out_kernel<<<gOut, blk, 0, stream>>>(bufA, fW2, fb2, out, N);
}

// Round 3
// 919.893 us; speedup vs baseline: 9.3817x; 1.0303x over previous
//
#include <hip/hip_runtime.h>
#include <hip/hip_bf16.h>

#define DIM 128

// ---------------- degree / dinv ----------------
__global__ __launch_bounds__(256) void deg_count_kernel(const int* __restrict__ dst,
                                                        int* __restrict__ deg, int E) {
    int e = blockIdx.x * 256 + threadIdx.x;
    if (e < E) atomicAdd(&deg[dst[e]], 1);
}

__global__ __launch_bounds__(256) void dinv_kernel(const int* __restrict__ deg,
                                                   float* __restrict__ dinv, int N) {
    int i = blockIdx.x * 256 + threadIdx.x;
    if (i < N) dinv[i] = rsqrtf((float)(deg[i] + 1));   // +1 self-loop
}

// ---------------- exclusive scan (3-kernel, N ~ 100K) ----------------
__global__ __launch_bounds__(256) void scan_block_sums(const int* __restrict__ deg,
                                                       int* __restrict__ bsum, int N) {
    int i = blockIdx.x * 256 + threadIdx.x;
    int v = (i < N) ? deg[i] : 0;
#pragma unroll
    for (int off = 32; off; off >>= 1) v += __shfl_down(v, off);
    __shared__ int ws[4];
    if ((threadIdx.x & 63) == 0) ws[threadIdx.x >> 6] = v;
    __syncthreads();
    if (threadIdx.x == 0) bsum[blockIdx.x] = ws[0] + ws[1] + ws[2] + ws[3];
}

__global__ __launch_bounds__(256) void scan_bsum_kernel(int* __restrict__ bsum, int nb) {
    __shared__ int sm[256];
    __shared__ int carry_s;
    if (threadIdx.x == 0) carry_s = 0;
    __syncthreads();
    for (int base = 0; base < nb; base += 256) {
        int i = base + threadIdx.x;
        int v = (i < nb) ? bsum[i] : 0;
        int c = carry_s;
        sm[threadIdx.x] = v;
        __syncthreads();
        for (int off = 1; off < 256; off <<= 1) {
            int t = (threadIdx.x >= off) ? sm[threadIdx.x - off] : 0;
            __syncthreads();
            sm[threadIdx.x] += t;
            __syncthreads();
        }
        int incl = sm[threadIdx.x];
        if (i < nb) bsum[i] = c + incl - v;   // exclusive
        __syncthreads();
        if (threadIdx.x == 0) carry_s = c + sm[255];
        __syncthreads();
    }
}

__global__ __launch_bounds__(256) void scan_finish_kernel(const int* __restrict__ deg,
                                                          const int* __restrict__ bsum,
                                                          int* __restrict__ rowptr,
                                                          int* __restrict__ cursor, int N) {
    __shared__ int sm[256];
    int i = blockIdx.x * 256 + threadIdx.x;
    int v = (i < N) ? deg[i] : 0;
    sm[threadIdx.x] = v;
    __syncthreads();
    for (int off = 1; off < 256; off <<= 1) {
        int t = (threadIdx.x >= off) ? sm[threadIdx.x - off] : 0;
        __syncthreads();
        sm[threadIdx.x] += t;
        __syncthreads();
    }
    int excl = sm[threadIdx.x] - v + bsum[blockIdx.x];
    if (i < N) { rowptr[i] = excl; cursor[i] = excl; }
    if (i == N - 1) rowptr[N] = excl + v;   // == E
}

__global__ __launch_bounds__(256) void csr_fill_kernel(const int* __restrict__ src,
                                                       const int* __restrict__ dst,
                                                       int* __restrict__ cursor,
                                                       int* __restrict__ colidx, int E) {
    int e = blockIdx.x * 256 + threadIdx.x;
    if (e < E) {
        int p = atomicAdd(&cursor[dst[e]], 1);
        colidx[p] = src[e];
    }
}

// ---------------- GEMM 128 -> 128, v2 ----------------
// Block: 1024 threads = 16 waves, 128 rows. Wave w owns cols [8w, 8w+8).
// Lane l owns rows row0+l and row0+64+l. X staged k-group-major in LDS
// (Xs4[kk][row], pad 129): 2 ds_read_b128 per lane per 4 k-steps for 64 FMAs
// -> FMA-bound. W read via wave-uniform addresses (scalar path), 4KB/wave once.
template<bool SCALE, bool BIAS, bool RELU>
__global__ __launch_bounds__(1024, 4) void gemm128_v2(
    const float* __restrict__ X, const float* __restrict__ W,
    const float* __restrict__ b, const float* __restrict__ dinv,
    float* __restrict__ Y, int N)
{
    __shared__ float4 Xs4[32 * 129];   // 66048 B -> 2 blocks/CU
    const int tid  = threadIdx.x;
    const int row0 = blockIdx.x * 128;
    const int lane = tid & 63;
    const int wv   = __builtin_amdgcn_readfirstlane(tid >> 6);  // 0..15, wave-uniform
    const int j0   = wv * 8;

    // stage X: global row-major float4 (coalesced) -> LDS k-group-major
    const float4* X4 = (const float4*)X;
#pragma unroll
    for (int i = 0; i < 4; ++i) {
        int f   = tid + 1024 * i;      // 0..4095
        int row = f >> 5;              // 0..127
        int kk  = f & 31;              // k-group
        float4 v = float4{0.f, 0.f, 0.f, 0.f};
        if (row0 + row < N) v = X4[(size_t)(row0 + row) * 32 + kk];
        Xs4[kk * 129 + row] = v;
    }
    __syncthreads();

    float acc[2][8];
#pragma unroll
    for (int r = 0; r < 2; ++r)
#pragma unroll
        for (int c = 0; c < 8; ++c) acc[r][c] = 0.f;

#pragma unroll 4
    for (int kk = 0; kk < 32; ++kk) {
        float4 xa = Xs4[kk * 129 + lane];
        float4 xb = Xs4[kk * 129 + 64 + lane];
        const float* wp = W + (kk * 4) * DIM + j0;   // wave-uniform
        float ws[32];
        *(float4*)&ws[0]  = *(const float4*)(wp + 0);
        *(float4*)&ws[4]  = *(const float4*)(wp + 4);
        *(float4*)&ws[8]  = *(const float4*)(wp + DIM);
        *(float4*)&ws[12] = *(const float4*)(wp + DIM + 4);
        *(float4*)&ws[16] = *(const float4*)(wp + 2 * DIM);
        *(float4*)&ws[20] = *(const float4*)(wp + 2 * DIM + 4);
        *(float4*)&ws[24] = *(const float4*)(wp + 3 * DIM);
        *(float4*)&ws[28] = *(const float4*)(wp + 3 * DIM + 4);
        const float* xap = (const float*)&xa;
        const float* xbp = (const float*)&xb;
#pragma unroll
        for (int k = 0; k < 4; ++k) {
#pragma unroll
            for (int c = 0; c < 8; ++c) {
                acc[0][c] = fmaf(xap[k], ws[k * 8 + c], acc[0][c]);
                acc[1][c] = fmaf(xbp[k], ws[k * 8 + c], acc[1][c]);
            }
        }
    }

    float bb[8];
    if (BIAS) {
        *(float4*)&bb[0] = *(const float4*)&b[j0];
        *(float4*)&bb[4] = *(const float4*)&b[j0 + 4];
    } else {
#pragma unroll
        for (int c = 0; c < 8; ++c) bb[c] = 0.f;
    }

#pragma unroll
    for (int r = 0; r < 2; ++r) {
        int row = row0 + lane + r * 64;
        if (row < N) {
            float s = SCALE ? dinv[row] : 1.0f;
            float o[8];
#pragma unroll
            for (int c = 0; c < 8; ++c) {
                o[c] = fmaf(acc[r][c], s, bb[c]);
                if (RELU) o[c] = fmaxf(o[c], 0.f);
            }
            *(float4*)&Y[(size_t)row * DIM + j0]     = *(float4*)&o[0];
            *(float4*)&Y[(size_t)row * DIM + j0 + 4] = *(float4*)&o[4];
        }
    }
}

// ---------------- pull-gather + fused epilogue ----------------
__global__ __launch_bounds__(256) void gather_kernel(
    const int* __restrict__ rowptr, const int* __restrict__ colidx,
    const float* __restrict__ H, const float* __restrict__ b,
    const float* __restrict__ dinv, float* __restrict__ Y, int N)
{
    int t = blockIdx.x * 256 + threadIdx.x;
    int node = t >> 5;
    if (node >= N) return;
    int c = (t & 31) * 4;

    int beg = rowptr[node];
    int end = rowptr[node + 1];

    float4 acc = *(const float4*)&H[(size_t)node * DIM + c];   // self-loop
    int e = beg;
    for (; e + 1 < end; e += 2) {
        int s0 = colidx[e];
        int s1 = colidx[e + 1];
        float4 v0 = *(const float4*)&H[(size_t)s0 * DIM + c];
        float4 v1 = *(const float4*)&H[(size_t)s1 * DIM + c];
        acc.x += v0.x + v1.x; acc.y += v0.y + v1.y;
        acc.z += v0.z + v1.z; acc.w += v0.w + v1.w;
    }
    if (e < end) {
        int s0 = colidx[e];
        float4 v0 = *(const float4*)&H[(size_t)s0 * DIM + c];
        acc.x += v0.x; acc.y += v0.y; acc.z += v0.z; acc.w += v0.w;
    }

    float sc = dinv[node];
    float4 bb = *(const float4*)&b[c];
    float4 o;
    o.x = fmaxf(fmaf(acc.x, sc, bb.x), 0.f);
    o.y = fmaxf(fmaf(acc.y, sc, bb.y), 0.f);
    o.z = fmaxf(fmaf(acc.z, sc, bb.z), 0.f);
    o.w = fmaxf(fmaf(acc.w, sc, bb.w), 0.f);
    *(float4*)&Y[(size_t)node * DIM + c] = o;
}

// ---------------- final 128 -> 10 GEMM ----------------
__global__ __launch_bounds__(256) void gemm_out_kernel(
    const float* __restrict__ X, const float* __restrict__ W,
    const float* __restrict__ b, float* __restrict__ out, int N)
{
    __shared__ float Wl[DIM * 10];
    __shared__ float bl[16];
    __shared__ float Xs[64 * DIM];
    int tid = threadIdx.x;
    for (int i = tid; i < DIM * 10; i += 256) Wl[i] = W[i];
    if (tid < 10) bl[tid] = b[tid];
    int row0 = blockIdx.x * 64;
    for (int i = tid * 4; i < 64 * DIM; i += 256 * 4) {
        int r = row0 + (i >> 7);
        float4 v;
        if (r < N) v = *(const float4*)&X[row0 * DIM + i];
        else       v = float4{0.f, 0.f, 0.f, 0.f};
        *(float4*)&Xs[i] = v;
    }
    __syncthreads();
    for (int oi = tid; oi < 64 * 10; oi += 256) {
        int r = oi / 10;
        int cc = oi - r * 10;
        int row = row0 + r;
        if (row >= N) continue;
        float acc = 0.f;
#pragma unroll 8
        for (int k = 0; k < DIM; ++k)
            acc = fmaf(Xs[r * DIM + k], Wl[k * 10 + cc], acc);
        out[row * 10 + cc] = acc + bl[cc];
    }
}

extern "C" void kernel_launch(void* const* d_in, const int* in_sizes, int n_in,
                              void* d_out, int out_size, void* d_ws, size_t ws_size,
                              hipStream_t stream) {
    const float* x   = (const float*)d_in[0];
    const int*   ei  = (const int*)  d_in[1];
    const float* W1  = (const float*)d_in[2];
    const float* b1  = (const float*)d_in[3];
    const float* W2  = (const float*)d_in[4];
    const float* b2  = (const float*)d_in[5];
    const float* W3  = (const float*)d_in[6];
    const float* b3  = (const float*)d_in[7];
    const float* fW1 = (const float*)d_in[8];
    const float* fb1 = (const float*)d_in[9];
    const float* fW2 = (const float*)d_in[10];
    const float* fb2 = (const float*)d_in[11];
    float* out = (float*)d_out;

    const int N = in_sizes[0] / DIM;     // 100000
    const int E = in_sizes[1] / 2;       // 1600000
    const int* srcI = ei;
    const int* dstI = ei + E;
    const int nb = (N + 255) / 256;      // scan blocks

    // ---- workspace carve-up (256B aligned) ----
    char* ws = (char*)d_ws;
    size_t off = 0;
    auto carve = [&](size_t bytes) { void* p = ws + off; off = (off + bytes + 255) & ~(size_t)255; return p; };
    float* dinv   = (float*)carve((size_t)N * 4);
    int*   deg    = (int*)  carve((size_t)N * 4);
    int*   rowptr = (int*)  carve((size_t)(N + 1) * 4);
    int*   cursor = (int*)  carve((size_t)N * 4);
    int*   bsum   = (int*)  carve((size_t)nb * 4);
    int*   colidx = (int*)  carve((size_t)E * 4);
    float* bufA   = (float*)carve((size_t)N * DIM * 4);
    float* bufB   = (float*)carve((size_t)N * DIM * 4);

    dim3 blk(256);
    int gN   = (N + 255) / 256;
    int gE   = (E + 255) / 256;
    int gG   = (N + 127) / 128;          // gemm v2 blocks (1024 thr)
    int gGa  = (int)(((long long)N * 32 + 255) / 256);
    int gOut = (N + 63) / 64;

    // ---- CSR build (per launch; d_ws is re-poisoned every call) ----
    hipMemsetAsync(deg, 0, (size_t)N * 4, stream);
    deg_count_kernel<<<gE, blk, 0, stream>>>(dstI, deg, E);
    dinv_kernel<<<gN, blk, 0, stream>>>(deg, dinv, N);
    scan_block_sums<<<nb, blk, 0, stream>>>(deg, bsum, N);
    scan_bsum_kernel<<<1, blk, 0, stream>>>(bsum, nb);
    scan_finish_kernel<<<nb, blk, 0, stream>>>(deg, bsum, rowptr, cursor, N);
    csr_fill_kernel<<<gE, blk, 0, stream>>>(srcI, dstI, cursor, colidx, E);

    // ---- GCN layer 1: x -> bufB
    gemm128_v2<true, false, false><<<gG, 1024, 0, stream>>>(x, W1, nullptr, dinv, bufA, N);
    gather_kernel<<<gGa, blk, 0, stream>>>(rowptr, colidx, bufA, b1, dinv, bufB, N);

    // ---- GCN layer 2
    gemm128_v2<true, false, false><<<gG, 1024, 0, stream>>>(bufB, W2, nullptr, dinv, bufA, N);
    gather_kernel<<<gGa, blk, 0, stream>>>(rowptr, colidx, bufA, b2, dinv, bufB, N);

    // ---- GCN layer 3
    gemm128_v2<true, false, false><<<gG, 1024, 0, stream>>>(bufB, W3, nullptr, dinv, bufA, N);
    gather_kernel<<<gGa, blk, 0, stream>>>(rowptr, colidx, bufA, b3, dinv, bufB, N);

    // ---- FFN head
    gemm128_v2<false, true, true><<<gG, 1024, 0, stream>>>(bufB, fW1, fb1, nullptr, bufA, N);
    gemm_out_kernel<<<gOut, blk, 0, stream>>>(bufA, fW2, fb2, out, N);
}

// Round 4
// 842.758 us; speedup vs baseline: 10.2404x; 1.0915x over previous
//
#include <hip/hip_runtime.h>
#include <hip/hip_bf16.h>

#define DIM 128

typedef __attribute__((ext_vector_type(8))) short bf16x8;
typedef __attribute__((ext_vector_type(4))) float f32x4;

union Frag { unsigned int u[4]; bf16x8 v; };

// fp32[8] -> packed bf16 hi (round-half-up) + bf16 lo (truncated residual).
// Element j = k index ascending; uint p holds k=2p (low 16) and k=2p+1 (high 16).
__device__ __forceinline__ void cvt_hilo(const float* __restrict__ x, Frag& hi, Frag& lo) {
#pragma unroll
    for (int p = 0; p < 4; ++p) {
        float x0 = x[2 * p], x1 = x[2 * p + 1];
        unsigned int h0 = (__float_as_uint(x0) + 0x8000u) & 0xffff0000u;
        unsigned int h1 = (__float_as_uint(x1) + 0x8000u) & 0xffff0000u;
        hi.u[p] = (h0 >> 16) | h1;
        float d0 = x0 - __uint_as_float(h0);
        float d1 = x1 - __uint_as_float(h1);
        lo.u[p] = (__float_as_uint(d0) >> 16) | (__float_as_uint(d1) & 0xffff0000u);
    }
}

// ---------------- degree / dinv ----------------
__global__ __launch_bounds__(256) void deg_count_kernel(const int* __restrict__ dst,
                                                        int* __restrict__ deg, int E) {
    int e = blockIdx.x * 256 + threadIdx.x;
    if (e < E) atomicAdd(&deg[dst[e]], 1);
}

__global__ __launch_bounds__(256) void dinv_kernel(const int* __restrict__ deg,
                                                   float* __restrict__ dinv, int N) {
    int i = blockIdx.x * 256 + threadIdx.x;
    if (i < N) dinv[i] = rsqrtf((float)(deg[i] + 1));   // +1 self-loop
}

// ---------------- exclusive scan (3-kernel, N ~ 100K) ----------------
__global__ __launch_bounds__(256) void scan_block_sums(const int* __restrict__ deg,
                                                       int* __restrict__ bsum, int N) {
    int i = blockIdx.x * 256 + threadIdx.x;
    int v = (i < N) ? deg[i] : 0;
#pragma unroll
    for (int off = 32; off; off >>= 1) v += __shfl_down(v, off);
    __shared__ int ws[4];
    if ((threadIdx.x & 63) == 0) ws[threadIdx.x >> 6] = v;
    __syncthreads();
    if (threadIdx.x == 0) bsum[blockIdx.x] = ws[0] + ws[1] + ws[2] + ws[3];
}

__global__ __launch_bounds__(256) void scan_bsum_kernel(int* __restrict__ bsum, int nb) {
    __shared__ int sm[256];
    __shared__ int carry_s;
    if (threadIdx.x == 0) carry_s = 0;
    __syncthreads();
    for (int base = 0; base < nb; base += 256) {
        int i = base + threadIdx.x;
        int v = (i < nb) ? bsum[i] : 0;
        int c = carry_s;
        sm[threadIdx.x] = v;
        __syncthreads();
        for (int off = 1; off < 256; off <<= 1) {
            int t = (threadIdx.x >= off) ? sm[threadIdx.x - off] : 0;
            __syncthreads();
            sm[threadIdx.x] += t;
            __syncthreads();
        }
        int incl = sm[threadIdx.x];
        if (i < nb) bsum[i] = c + incl - v;   // exclusive
        __syncthreads();
        if (threadIdx.x == 0) carry_s = c + sm[255];
        __syncthreads();
    }
}

__global__ __launch_bounds__(256) void scan_finish_kernel(const int* __restrict__ deg,
                                                          const int* __restrict__ bsum,
                                                          int* __restrict__ rowptr,
                                                          int* __restrict__ cursor, int N) {
    __shared__ int sm[256];
    int i = blockIdx.x * 256 + threadIdx.x;
    int v = (i < N) ? deg[i] : 0;
    sm[threadIdx.x] = v;
    __syncthreads();
    for (int off = 1; off < 256; off <<= 1) {
        int t = (threadIdx.x >= off) ? sm[threadIdx.x - off] : 0;
        __syncthreads();
        sm[threadIdx.x] += t;
        __syncthreads();
    }
    int excl = sm[threadIdx.x] - v + bsum[blockIdx.x];
    if (i < N) { rowptr[i] = excl; cursor[i] = excl; }
    if (i == N - 1) rowptr[N] = excl + v;   // == E
}

__global__ __launch_bounds__(256) void csr_fill_kernel(const int* __restrict__ src,
                                                       const int* __restrict__ dst,
                                                       int* __restrict__ cursor,
                                                       int* __restrict__ colidx, int E) {
    int e = blockIdx.x * 256 + threadIdx.x;
    if (e < E) {
        int p = atomicAdd(&cursor[dst[e]], 1);
        colidx[p] = src[e];
    }
}

// ---------------- GEMM 128 -> 128 via split-fp32 bf16 MFMA ----------------
// Y = (X @ W) [* dinv[row]] [+ b] [relu], X:[N,128], W:[128,128].
// x = hi + lo (bf16 each); X@W ~= Xhi@Whi + Xhi@Wlo + Xlo@Whi (fp32 acc in MFMA).
// Block 256 thr = 2x2 waves; wave = 64 rows x 64 cols = 4x4 tiles of 16x16, K chunks of 32.
// No LDS: A from X (2 dwordx4/lane), B from W column-wise (8 dwords/lane, 64B coalesced).
template<bool SCALE, bool BIAS, bool RELU>
__global__ __launch_bounds__(256, 2) void gemm128_mfma(
    const float* __restrict__ X, const float* __restrict__ W,
    const float* __restrict__ b, const float* __restrict__ dinv,
    float* __restrict__ Y, int N)
{
    const int tid  = threadIdx.x;
    const int lane = tid & 63;
    const int wv   = tid >> 6;      // 0..3
    const int wr   = wv >> 1;       // row half of block tile
    const int wc   = wv & 1;        // col half
    const int m    = lane & 15;
    const int quad = lane >> 4;

    const int row0 = blockIdx.x * 128 + wr * 64;
    const int col0 = wc * 64;

    f32x4 acc[4][4];
#pragma unroll
    for (int rt = 0; rt < 4; ++rt)
#pragma unroll
        for (int ct = 0; ct < 4; ++ct) acc[rt][ct] = f32x4{0.f, 0.f, 0.f, 0.f};

    for (int kc = 0; kc < 4; ++kc) {
        const int k0 = kc * 32 + quad * 8;

        // B fragments: W[k0..k0+7][col], col = col0 + ct*16 + m
        Frag bhi[4], blo[4];
#pragma unroll
        for (int ct = 0; ct < 4; ++ct) {
            int col = col0 + ct * 16 + m;
            float wv8[8];
#pragma unroll
            for (int j = 0; j < 8; ++j)
                wv8[j] = W[(size_t)(k0 + j) * DIM + col];
            cvt_hilo(wv8, bhi[ct], blo[ct]);
        }

        // A fragments: X[row][k0..k0+7], row = row0 + rt*16 + m
        Frag ahi[4], alo[4];
#pragma unroll
        for (int rt = 0; rt < 4; ++rt) {
            int row = row0 + rt * 16 + m;
            if (row > N - 1) row = N - 1;
            const float* xp = &X[(size_t)row * DIM + k0];
            float xv8[8];
            *(float4*)&xv8[0] = *(const float4*)xp;
            *(float4*)&xv8[4] = *(const float4*)(xp + 4);
            cvt_hilo(xv8, ahi[rt], alo[rt]);
        }

#pragma unroll
        for (int rt = 0; rt < 4; ++rt)
#pragma unroll
            for (int ct = 0; ct < 4; ++ct) {
                acc[rt][ct] = __builtin_amdgcn_mfma_f32_16x16x32_bf16(ahi[rt].v, bhi[ct].v, acc[rt][ct], 0, 0, 0);
                acc[rt][ct] = __builtin_amdgcn_mfma_f32_16x16x32_bf16(ahi[rt].v, blo[ct].v, acc[rt][ct], 0, 0, 0);
                acc[rt][ct] = __builtin_amdgcn_mfma_f32_16x16x32_bf16(alo[rt].v, bhi[ct].v, acc[rt][ct], 0, 0, 0);
            }
    }

    // epilogue: C/D layout col = lane&15, row = quad*4 + reg
    float bias[4];
#pragma unroll
    for (int ct = 0; ct < 4; ++ct)
        bias[ct] = BIAS ? b[col0 + ct * 16 + m] : 0.f;

#pragma unroll
    for (int rt = 0; rt < 4; ++rt) {
#pragma unroll
        for (int r = 0; r < 4; ++r) {
            int grow = row0 + rt * 16 + quad * 4 + r;
            if (grow >= N) continue;
            float s = SCALE ? dinv[grow] : 1.0f;
#pragma unroll
            for (int ct = 0; ct < 4; ++ct) {
                float o = fmaf(acc[rt][ct][r], s, bias[ct]);
                if (RELU) o = fmaxf(o, 0.f);
                Y[(size_t)grow * DIM + col0 + ct * 16 + m] = o;
            }
        }
    }
}

// ---------------- pull-gather + fused epilogue ----------------
__global__ __launch_bounds__(256) void gather_kernel(
    const int* __restrict__ rowptr, const int* __restrict__ colidx,
    const float* __restrict__ H, const float* __restrict__ b,
    const float* __restrict__ dinv, float* __restrict__ Y, int N)
{
    int t = blockIdx.x * 256 + threadIdx.x;
    int node = t >> 5;
    if (node >= N) return;
    int c = (t & 31) * 4;

    int beg = rowptr[node];
    int end = rowptr[node + 1];

    float4 acc = *(const float4*)&H[(size_t)node * DIM + c];   // self-loop
    int e = beg;
    for (; e + 1 < end; e += 2) {
        int s0 = colidx[e];
        int s1 = colidx[e + 1];
        float4 v0 = *(const float4*)&H[(size_t)s0 * DIM + c];
        float4 v1 = *(const float4*)&H[(size_t)s1 * DIM + c];
        acc.x += v0.x + v1.x; acc.y += v0.y + v1.y;
        acc.z += v0.z + v1.z; acc.w += v0.w + v1.w;
    }
    if (e < end) {
        int s0 = colidx[e];
        float4 v0 = *(const float4*)&H[(size_t)s0 * DIM + c];
        acc.x += v0.x; acc.y += v0.y; acc.z += v0.z; acc.w += v0.w;
    }

    float sc = dinv[node];
    float4 bb = *(const float4*)&b[c];
    float4 o;
    o.x = fmaxf(fmaf(acc.x, sc, bb.x), 0.f);
    o.y = fmaxf(fmaf(acc.y, sc, bb.y), 0.f);
    o.z = fmaxf(fmaf(acc.z, sc, bb.z), 0.f);
    o.w = fmaxf(fmaf(acc.w, sc, bb.w), 0.f);
    *(float4*)&Y[(size_t)node * DIM + c] = o;
}

// ---------------- final 128 -> 10 GEMM ----------------
__global__ __launch_bounds__(256) void gemm_out_kernel(
    const float* __restrict__ X, const float* __restrict__ W,
    const float* __restrict__ b, float* __restrict__ out, int N)
{
    __shared__ float Wl[DIM * 10];
    __shared__ float bl[16];
    __shared__ float Xs[64 * DIM];
    int tid = threadIdx.x;
    for (int i = tid; i < DIM * 10; i += 256) Wl[i] = W[i];
    if (tid < 10) bl[tid] = b[tid];
    int row0 = blockIdx.x * 64;
    for (int i = tid * 4; i < 64 * DIM; i += 256 * 4) {
        int r = row0 + (i >> 7);
        float4 v;
        if (r < N) v = *(const float4*)&X[row0 * DIM + i];
        else       v = float4{0.f, 0.f, 0.f, 0.f};
        *(float4*)&Xs[i] = v;
    }
    __syncthreads();
    for (int oi = tid; oi < 64 * 10; oi += 256) {
        int r = oi / 10;
        int cc = oi - r * 10;
        int row = row0 + r;
        if (row >= N) continue;
        float acc = 0.f;
#pragma unroll 8
        for (int k = 0; k < DIM; ++k)
            acc = fmaf(Xs[r * DIM + k], Wl[k * 10 + cc], acc);
        out[row * 10 + cc] = acc + bl[cc];
    }
}

extern "C" void kernel_launch(void* const* d_in, const int* in_sizes, int n_in,
                              void* d_out, int out_size, void* d_ws, size_t ws_size,
                              hipStream_t stream) {
    const float* x   = (const float*)d_in[0];
    const int*   ei  = (const int*)  d_in[1];
    const float* W1  = (const float*)d_in[2];
    const float* b1  = (const float*)d_in[3];
    const float* W2  = (const float*)d_in[4];
    const float* b2  = (const float*)d_in[5];
    const float* W3  = (const float*)d_in[6];
    const float* b3  = (const float*)d_in[7];
    const float* fW1 = (const float*)d_in[8];
    const float* fb1 = (const float*)d_in[9];
    const float* fW2 = (const float*)d_in[10];
    const float* fb2 = (const float*)d_in[11];
    float* out = (float*)d_out;

    const int N = in_sizes[0] / DIM;     // 100000
    const int E = in_sizes[1] / 2;       // 1600000
    const int* srcI = ei;
    const int* dstI = ei + E;
    const int nb = (N + 255) / 256;      // scan blocks

    // ---- workspace carve-up (256B aligned) ----
    char* ws = (char*)d_ws;
    size_t off = 0;
    auto carve = [&](size_t bytes) { void* p = ws + off; off = (off + bytes + 255) & ~(size_t)255; return p; };
    float* dinv   = (float*)carve((size_t)N * 4);
    int*   deg    = (int*)  carve((size_t)N * 4);
    int*   rowptr = (int*)  carve((size_t)(N + 1) * 4);
    int*   cursor = (int*)  carve((size_t)N * 4);
    int*   bsum   = (int*)  carve((size_t)nb * 4);
    int*   colidx = (int*)  carve((size_t)E * 4);
    float* bufA   = (float*)carve((size_t)N * DIM * 4);
    float* bufB   = (float*)carve((size_t)N * DIM * 4);

    dim3 blk(256);
    int gN   = (N + 255) / 256;
    int gE   = (E + 255) / 256;
    int gG   = (N + 127) / 128;          // mfma gemm blocks
    int gGa  = (int)(((long long)N * 32 + 255) / 256);
    int gOut = (N + 63) / 64;

    // ---- CSR build (per launch; d_ws is re-poisoned every call) ----
    hipMemsetAsync(deg, 0, (size_t)N * 4, stream);
    deg_count_kernel<<<gE, blk, 0, stream>>>(dstI, deg, E);
    dinv_kernel<<<gN, blk, 0, stream>>>(deg, dinv, N);
    scan_block_sums<<<nb, blk, 0, stream>>>(deg, bsum, N);
    scan_bsum_kernel<<<1, blk, 0, stream>>>(bsum, nb);
    scan_finish_kernel<<<nb, blk, 0, stream>>>(deg, bsum, rowptr, cursor, N);
    csr_fill_kernel<<<gE, blk, 0, stream>>>(srcI, dstI, cursor, colidx, E);

    // ---- GCN layer 1: x -> bufB
    gemm128_mfma<true, false, false><<<gG, blk, 0, stream>>>(x, W1, nullptr, dinv, bufA, N);
    gather_kernel<<<gGa, blk, 0, stream>>>(rowptr, colidx, bufA, b1, dinv, bufB, N);

    // ---- GCN layer 2
    gemm128_mfma<true, false, false><<<gG, blk, 0, stream>>>(bufB, W2, nullptr, dinv, bufA, N);
    gather_kernel<<<gGa, blk, 0, stream>>>(rowptr, colidx, bufA, b2, dinv, bufB, N);

    // ---- GCN layer 3
    gemm128_mfma<true, false, false><<<gG, blk, 0, stream>>>(bufB, W3, nullptr, dinv, bufA, N);
    gather_kernel<<<gGa, blk, 0, stream>>>(rowptr, colidx, bufA, b3, dinv, bufB, N);

    // ---- FFN head
    gemm128_mfma<false, true, true><<<gG, blk, 0, stream>>>(bufB, fW1, fb1, nullptr, bufA, N);
    gemm_out_kernel<<<gOut, blk, 0, stream>>>(bufA, fW2, fb2, out, N);
}

// Round 5
// 805.366 us; speedup vs baseline: 10.7158x; 1.0464x over previous
//
#include <hip/hip_runtime.h>
#include <hip/hip_bf16.h>

#define DIM 128

typedef __attribute__((ext_vector_type(8))) short bf16x8;
typedef __attribute__((ext_vector_type(4))) float f32x4;

union Frag { unsigned int u[4]; bf16x8 v; uint4 q; };

// fp32[8] -> packed bf16 hi (round-half-up) + bf16 lo (truncated residual).
// uint p holds k=2p (low 16) and k=2p+1 (high 16).
__device__ __forceinline__ void cvt_hilo(const float* __restrict__ x, Frag& hi, Frag& lo) {
#pragma unroll
    for (int p = 0; p < 4; ++p) {
        float x0 = x[2 * p], x1 = x[2 * p + 1];
        unsigned int h0 = (__float_as_uint(x0) + 0x8000u) & 0xffff0000u;
        unsigned int h1 = (__float_as_uint(x1) + 0x8000u) & 0xffff0000u;
        hi.u[p] = (h0 >> 16) | h1;
        float d0 = x0 - __uint_as_float(h0);
        float d1 = x1 - __uint_as_float(h1);
        lo.u[p] = (__float_as_uint(d0) >> 16) | (__float_as_uint(d1) & 0xffff0000u);
    }
}

// ---------------- degree / dinv ----------------
__global__ __launch_bounds__(256) void deg_count_kernel(const int* __restrict__ dst,
                                                        int* __restrict__ deg, int E) {
    int e = blockIdx.x * 256 + threadIdx.x;
    if (e < E) atomicAdd(&deg[dst[e]], 1);
}

__global__ __launch_bounds__(256) void dinv_kernel(const int* __restrict__ deg,
                                                   float* __restrict__ dinv, int N) {
    int i = blockIdx.x * 256 + threadIdx.x;
    if (i < N) dinv[i] = rsqrtf((float)(deg[i] + 1));   // +1 self-loop
}

// ---------------- exclusive scan (3-kernel, N ~ 100K) ----------------
__global__ __launch_bounds__(256) void scan_block_sums(const int* __restrict__ deg,
                                                       int* __restrict__ bsum, int N) {
    int i = blockIdx.x * 256 + threadIdx.x;
    int v = (i < N) ? deg[i] : 0;
#pragma unroll
    for (int off = 32; off; off >>= 1) v += __shfl_down(v, off);
    __shared__ int ws[4];
    if ((threadIdx.x & 63) == 0) ws[threadIdx.x >> 6] = v;
    __syncthreads();
    if (threadIdx.x == 0) bsum[blockIdx.x] = ws[0] + ws[1] + ws[2] + ws[3];
}

__global__ __launch_bounds__(256) void scan_bsum_kernel(int* __restrict__ bsum, int nb) {
    __shared__ int sm[256];
    __shared__ int carry_s;
    if (threadIdx.x == 0) carry_s = 0;
    __syncthreads();
    for (int base = 0; base < nb; base += 256) {
        int i = base + threadIdx.x;
        int v = (i < nb) ? bsum[i] : 0;
        int c = carry_s;
        sm[threadIdx.x] = v;
        __syncthreads();
        for (int off = 1; off < 256; off <<= 1) {
            int t = (threadIdx.x >= off) ? sm[threadIdx.x - off] : 0;
            __syncthreads();
            sm[threadIdx.x] += t;
            __syncthreads();
        }
        int incl = sm[threadIdx.x];
        if (i < nb) bsum[i] = c + incl - v;   // exclusive
        __syncthreads();
        if (threadIdx.x == 0) carry_s = c + sm[255];
        __syncthreads();
    }
}

__global__ __launch_bounds__(256) void scan_finish_kernel(const int* __restrict__ deg,
                                                          const int* __restrict__ bsum,
                                                          int* __restrict__ rowptr,
                                                          int* __restrict__ cursor, int N) {
    __shared__ int sm[256];
    int i = blockIdx.x * 256 + threadIdx.x;
    int v = (i < N) ? deg[i] : 0;
    sm[threadIdx.x] = v;
    __syncthreads();
    for (int off = 1; off < 256; off <<= 1) {
        int t = (threadIdx.x >= off) ? sm[threadIdx.x - off] : 0;
        __syncthreads();
        sm[threadIdx.x] += t;
        __syncthreads();
    }
    int excl = sm[threadIdx.x] - v + bsum[blockIdx.x];
    if (i < N) { rowptr[i] = excl; cursor[i] = excl; }
    if (i == N - 1) rowptr[N] = excl + v;   // == E
}

__global__ __launch_bounds__(256) void csr_fill_kernel(const int* __restrict__ src,
                                                       const int* __restrict__ dst,
                                                       int* __restrict__ cursor,
                                                       int* __restrict__ colidx, int E) {
    int e = blockIdx.x * 256 + threadIdx.x;
    if (e < E) {
        int p = atomicAdd(&cursor[dst[e]], 1);
        colidx[p] = src[e];
    }
}

// ---------------- W pre-conversion: fp32 W[128][128] -> per-lane hi/lo B-fragments ----
// Fragment id f = kc*8 + wc*4 + ct (kc: k-chunk of 32, wc: col half, ct: 16-col tile).
// Element (lane=quad*16+m, j): W[kc*32+quad*8+j][wc*64+ct*16+m]. 2048 threads per W.
__global__ __launch_bounds__(256) void wconv_kernel(const float* __restrict__ W,
                                                    uint4* __restrict__ WFhi,
                                                    uint4* __restrict__ WFlo) {
    int t = blockIdx.x * 256 + threadIdx.x;   // 0..2047
    int lane = t & 63;
    int f    = t >> 6;          // 0..31
    int kc   = f >> 3;
    int wc   = (f >> 2) & 1;
    int ct   = f & 3;
    int m    = lane & 15;
    int quad = lane >> 4;
    int col  = wc * 64 + ct * 16 + m;
    int k0   = kc * 32 + quad * 8;
    float wv8[8];
#pragma unroll
    for (int j = 0; j < 8; ++j) wv8[j] = W[(size_t)(k0 + j) * DIM + col];
    Frag hi, lo;
    cvt_hilo(wv8, hi, lo);
    WFhi[t] = hi.q;
    WFlo[t] = lo.q;
}

// ---------------- GEMM 128 -> 128 via split-fp32 bf16 MFMA, preconverted W ----
// Block 256 thr = 2x2 waves; wave = 64 rows x 64 cols = 4x4 tiles of 16x16, K chunks of 32.
// B frags: coalesced dwordx4 from preconverted WFhi/WFlo. A: 2 dwordx4 + cvt per (kc,rt).
template<bool SCALE, bool BIAS, bool RELU>
__global__ __launch_bounds__(256, 2) void gemm128_mfma(
    const float* __restrict__ X,
    const uint4* __restrict__ WFhi, const uint4* __restrict__ WFlo,
    const float* __restrict__ b, const float* __restrict__ dinv,
    float* __restrict__ Y, int N)
{
    const int tid  = threadIdx.x;
    const int lane = tid & 63;
    const int wv   = tid >> 6;      // 0..3
    const int wr   = wv >> 1;       // row half of block tile
    const int wc   = wv & 1;        // col half
    const int m    = lane & 15;
    const int quad = lane >> 4;

    const int row0 = blockIdx.x * 128 + wr * 64;
    const int col0 = wc * 64;

    f32x4 acc[4][4];
#pragma unroll
    for (int rt = 0; rt < 4; ++rt)
#pragma unroll
        for (int ct = 0; ct < 4; ++ct) acc[rt][ct] = f32x4{0.f, 0.f, 0.f, 0.f};

    for (int kc = 0; kc < 4; ++kc) {
        const int k0 = kc * 32 + quad * 8;

        // B fragments: preconverted, coalesced
        Frag bhi[4], blo[4];
#pragma unroll
        for (int ct = 0; ct < 4; ++ct) {
            int idx = (kc * 8 + wc * 4 + ct) * 64 + lane;
            bhi[ct].q = WFhi[idx];
            blo[ct].q = WFlo[idx];
        }

        // A fragments: X[row][k0..k0+7], row = row0 + rt*16 + m
        Frag ahi[4], alo[4];
#pragma unroll
        for (int rt = 0; rt < 4; ++rt) {
            int row = row0 + rt * 16 + m;
            if (row > N - 1) row = N - 1;
            const float* xp = &X[(size_t)row * DIM + k0];
            float xv8[8];
            *(float4*)&xv8[0] = *(const float4*)xp;
            *(float4*)&xv8[4] = *(const float4*)(xp + 4);
            cvt_hilo(xv8, ahi[rt], alo[rt]);
        }

#pragma unroll
        for (int rt = 0; rt < 4; ++rt)
#pragma unroll
            for (int ct = 0; ct < 4; ++ct) {
                acc[rt][ct] = __builtin_amdgcn_mfma_f32_16x16x32_bf16(ahi[rt].v, bhi[ct].v, acc[rt][ct], 0, 0, 0);
                acc[rt][ct] = __builtin_amdgcn_mfma_f32_16x16x32_bf16(ahi[rt].v, blo[ct].v, acc[rt][ct], 0, 0, 0);
                acc[rt][ct] = __builtin_amdgcn_mfma_f32_16x16x32_bf16(alo[rt].v, bhi[ct].v, acc[rt][ct], 0, 0, 0);
            }
    }

    // epilogue: C/D layout col = lane&15, row = quad*4 + reg
    float bias[4];
#pragma unroll
    for (int ct = 0; ct < 4; ++ct)
        bias[ct] = BIAS ? b[col0 + ct * 16 + m] : 0.f;

#pragma unroll
    for (int rt = 0; rt < 4; ++rt) {
#pragma unroll
        for (int r = 0; r < 4; ++r) {
            int grow = row0 + rt * 16 + quad * 4 + r;
            if (grow >= N) continue;
            float s = SCALE ? dinv[grow] : 1.0f;
#pragma unroll
            for (int ct = 0; ct < 4; ++ct) {
                float o = fmaf(acc[rt][ct][r], s, bias[ct]);
                if (RELU) o = fmaxf(o, 0.f);
                Y[(size_t)grow * DIM + col0 + ct * 16 + m] = o;
            }
        }
    }
}

// ---------------- pull-gather + fused epilogue ----------------
__global__ __launch_bounds__(256) void gather_kernel(
    const int* __restrict__ rowptr, const int* __restrict__ colidx,
    const float* __restrict__ H, const float* __restrict__ b,
    const float* __restrict__ dinv, float* __restrict__ Y, int N)
{
    int t = blockIdx.x * 256 + threadIdx.x;
    int node = t >> 5;
    if (node >= N) return;
    int c = (t & 31) * 4;

    int beg = rowptr[node];
    int end = rowptr[node + 1];

    float4 acc = *(const float4*)&H[(size_t)node * DIM + c];   // self-loop
    int e = beg;
    for (; e + 1 < end; e += 2) {
        int s0 = colidx[e];
        int s1 = colidx[e + 1];
        float4 v0 = *(const float4*)&H[(size_t)s0 * DIM + c];
        float4 v1 = *(const float4*)&H[(size_t)s1 * DIM + c];
        acc.x += v0.x + v1.x; acc.y += v0.y + v1.y;
        acc.z += v0.z + v1.z; acc.w += v0.w + v1.w;
    }
    if (e < end) {
        int s0 = colidx[e];
        float4 v0 = *(const float4*)&H[(size_t)s0 * DIM + c];
        acc.x += v0.x; acc.y += v0.y; acc.z += v0.z; acc.w += v0.w;
    }

    float sc = dinv[node];
    float4 bb = *(const float4*)&b[c];
    float4 o;
    o.x = fmaxf(fmaf(acc.x, sc, bb.x), 0.f);
    o.y = fmaxf(fmaf(acc.y, sc, bb.y), 0.f);
    o.z = fmaxf(fmaf(acc.z, sc, bb.z), 0.f);
    o.w = fmaxf(fmaf(acc.w, sc, bb.w), 0.f);
    *(float4*)&Y[(size_t)node * DIM + c] = o;
}

// ---------------- final 128 -> 10 GEMM ----------------
__global__ __launch_bounds__(256) void gemm_out_kernel(
    const float* __restrict__ X, const float* __restrict__ W,
    const float* __restrict__ b, float* __restrict__ out, int N)
{
    __shared__ float Wl[DIM * 10];
    __shared__ float bl[16];
    __shared__ float Xs[64 * DIM];
    int tid = threadIdx.x;
    for (int i = tid; i < DIM * 10; i += 256) Wl[i] = W[i];
    if (tid < 10) bl[tid] = b[tid];
    int row0 = blockIdx.x * 64;
    for (int i = tid * 4; i < 64 * DIM; i += 256 * 4) {
        int r = row0 + (i >> 7);
        float4 v;
        if (r < N) v = *(const float4*)&X[row0 * DIM + i];
        else       v = float4{0.f, 0.f, 0.f, 0.f};
        *(float4*)&Xs[i] = v;
    }
    __syncthreads();
    for (int oi = tid; oi < 64 * 10; oi += 256) {
        int r = oi / 10;
        int cc = oi - r * 10;
        int row = row0 + r;
        if (row >= N) continue;
        float acc = 0.f;
#pragma unroll 8
        for (int k = 0; k < DIM; ++k)
            acc = fmaf(Xs[r * DIM + k], Wl[k * 10 + cc], acc);
        out[row * 10 + cc] = acc + bl[cc];
    }
}

extern "C" void kernel_launch(void* const* d_in, const int* in_sizes, int n_in,
                              void* d_out, int out_size, void* d_ws, size_t ws_size,
                              hipStream_t stream) {
    const float* x   = (const float*)d_in[0];
    const int*   ei  = (const int*)  d_in[1];
    const float* W1  = (const float*)d_in[2];
    const float* b1  = (const float*)d_in[3];
    const float* W2  = (const float*)d_in[4];
    const float* b2  = (const float*)d_in[5];
    const float* W3  = (const float*)d_in[6];
    const float* b3  = (const float*)d_in[7];
    const float* fW1 = (const float*)d_in[8];
    const float* fb1 = (const float*)d_in[9];
    const float* fW2 = (const float*)d_in[10];
    const float* fb2 = (const float*)d_in[11];
    float* out = (float*)d_out;

    const int N = in_sizes[0] / DIM;     // 100000
    const int E = in_sizes[1] / 2;       // 1600000
    const int* srcI = ei;
    const int* dstI = ei + E;
    const int nb = (N + 255) / 256;      // scan blocks

    // ---- workspace carve-up (256B aligned) ----
    char* ws = (char*)d_ws;
    size_t off = 0;
    auto carve = [&](size_t bytes) { void* p = ws + off; off = (off + bytes + 255) & ~(size_t)255; return p; };
    float* dinv   = (float*)carve((size_t)N * 4);
    int*   deg    = (int*)  carve((size_t)N * 4);
    int*   rowptr = (int*)  carve((size_t)(N + 1) * 4);
    int*   cursor = (int*)  carve((size_t)N * 4);
    int*   bsum   = (int*)  carve((size_t)nb * 4);
    int*   colidx = (int*)  carve((size_t)E * 4);
    uint4* wfhi   = (uint4*)carve((size_t)4 * 2048 * 16);   // 4 matrices, hi frags
    uint4* wflo   = (uint4*)carve((size_t)4 * 2048 * 16);   // 4 matrices, lo frags
    float* bufA   = (float*)carve((size_t)N * DIM * 4);
    float* bufB   = (float*)carve((size_t)N * DIM * 4);

    dim3 blk(256);
    int gN   = (N + 255) / 256;
    int gE   = (E + 255) / 256;
    int gG   = (N + 127) / 128;          // mfma gemm blocks
    int gGa  = (int)(((long long)N * 32 + 255) / 256);
    int gOut = (N + 63) / 64;

    // ---- W pre-conversion (once per launch, ~1 us each) ----
    wconv_kernel<<<8, blk, 0, stream>>>(W1,  wfhi + 0 * 2048, wflo + 0 * 2048);
    wconv_kernel<<<8, blk, 0, stream>>>(W2,  wfhi + 1 * 2048, wflo + 1 * 2048);
    wconv_kernel<<<8, blk, 0, stream>>>(W3,  wfhi + 2 * 2048, wflo + 2 * 2048);
    wconv_kernel<<<8, blk, 0, stream>>>(fW1, wfhi + 3 * 2048, wflo + 3 * 2048);

    // ---- CSR build (per launch; d_ws is re-poisoned every call) ----
    hipMemsetAsync(deg, 0, (size_t)N * 4, stream);
    deg_count_kernel<<<gE, blk, 0, stream>>>(dstI, deg, E);
    dinv_kernel<<<gN, blk, 0, stream>>>(deg, dinv, N);
    scan_block_sums<<<nb, blk, 0, stream>>>(deg, bsum, N);
    scan_bsum_kernel<<<1, blk, 0, stream>>>(bsum, nb);
    scan_finish_kernel<<<nb, blk, 0, stream>>>(deg, bsum, rowptr, cursor, N);
    csr_fill_kernel<<<gE, blk, 0, stream>>>(srcI, dstI, cursor, colidx, E);

    // ---- GCN layer 1: x -> bufB
    gemm128_mfma<true, false, false><<<gG, blk, 0, stream>>>(x, wfhi + 0 * 2048, wflo + 0 * 2048, nullptr, dinv, bufA, N);
    gather_kernel<<<gGa, blk, 0, stream>>>(rowptr, colidx, bufA, b1, dinv, bufB, N);

    // ---- GCN layer 2
    gemm128_mfma<true, false, false><<<gG, blk, 0, stream>>>(bufB, wfhi + 1 * 2048, wflo + 1 * 2048, nullptr, dinv, bufA, N);
    gather_kernel<<<gGa, blk, 0, stream>>>(rowptr, colidx, bufA, b2, dinv, bufB, N);

    // ---- GCN layer 3
    gemm128_mfma<true, false, false><<<gG, blk, 0, stream>>>(bufB, wfhi + 2 * 2048, wflo + 2 * 2048, nullptr, dinv, bufA, N);
    gather_kernel<<<gGa, blk, 0, stream>>>(rowptr, colidx, bufA, b3, dinv, bufB, N);

    // ---- FFN head
    gemm128_mfma<false, true, true><<<gG, blk, 0, stream>>>(bufB, wfhi + 3 * 2048, wflo + 3 * 2048, fb1, nullptr, bufA, N);
    gemm_out_kernel<<<gOut, blk, 0, stream>>>(bufA, fW2, fb2, out, N);
}